// Round 12
// baseline (316.372 us; speedup 1.0000x reference)
//
#include <hip/hip_runtime.h>
#include <math.h>

// ---- problem constants ----
static constexpr int kN     = 40000;
static constexpr int kE     = 1000000;
static constexpr int kTDIM  = 16;
static constexpr int kG     = 64;
static constexpr int kPOOLC = 16;             // pooling chunks per group
static constexpr int kNB    = (kN + 255) / 256;   // 157 dst buckets (256 nodes each)
static constexpr int kCH    = 2048;               // edges per partition block
static constexpr int kPB    = (kE + kCH - 1) / kCH;  // 489 partition blocks
#define LN_EPS 1e-5f
#define NEG_SLOPE 0.2f

typedef __attribute__((ext_vector_type(8))) short bf16x8;
typedef __attribute__((ext_vector_type(4))) float f32x4;
typedef __attribute__((ext_vector_type(4))) unsigned uv4;

__device__ __forceinline__ float leaky(float v) {
  return fmaxf(v, NEG_SLOPE * v);
}

// round-to-nearest-even f32 -> bf16 (as ushort)
__device__ __forceinline__ unsigned short f2bf(float f) {
  unsigned u = __float_as_uint(f);
  unsigned r = u + 0x7fffu + ((u >> 16) & 1u);
  return (unsigned short)(r >> 16);
}
__device__ __forceinline__ float bflo(unsigned u) { return __uint_as_float(u << 16); }
__device__ __forceinline__ float bfhi(unsigned u) { return __uint_as_float(u & 0xffff0000u); }

// ---------- prep: classifier transpose + weight bf16 conversions + gbhist zero ----------
static constexpr int kP0 = 256 * 128;          // c1T
static constexpr int kP1 = kP0 + 128 * 128;    // pwb
static constexpr int kP2 = kP1 + 128 * 160;    // w0b (K padded 144->160)
static constexpr int kP3 = kP2 + 128 * 128;    // w1b
static constexpr int kP4 = kP3 + kNB;          // gbhist zero
__global__ void __launch_bounds__(256) k_prep(
    const float* __restrict__ c1w, float* __restrict__ c1T,
    const float* __restrict__ pw, unsigned short* __restrict__ pwb,
    const float* __restrict__ g0w, unsigned short* __restrict__ w0b,
    const float* __restrict__ g1w, unsigned short* __restrict__ w1b,
    int* __restrict__ gbhist) {
  int idx = blockIdx.x * 256 + threadIdx.x;
  if (idx < kP0) {
    int j = idx / 256, k = idx - j * 256;
    c1T[k * 128 + j] = c1w[idx];
  } else if (idx < kP1) {
    int i = idx - kP0;
    pwb[i] = f2bf(pw[i]);
  } else if (idx < kP2) {
    int i = idx - kP1;
    int j = i / 160, k = i - j * 160;
    w0b[i] = (k < 144) ? f2bf(g0w[j * 144 + k]) : (unsigned short)0;
  } else if (idx < kP3) {
    int i = idx - kP2;
    w1b[i] = f2bf(g1w[i]);
  } else if (idx < kP4) {
    gbhist[idx - kP3] = 0;
  }
}

// ---------- CSR build: 2-level bucket partition ----------
__global__ void __launch_bounds__(256) k_part0(const int* __restrict__ dst,
                                               int* __restrict__ gbhist) {
  __shared__ int h[kNB];
  int t = threadIdx.x;
  for (int i = t; i < kNB; i += 256) h[i] = 0;
  __syncthreads();
  int base = blockIdx.x * kCH;
#pragma unroll
  for (int i = 0; i < kCH / 256; ++i) {
    int e = base + i * 256 + t;
    if (e < kE) atomicAdd(&h[dst[e] >> 8], 1);
  }
  __syncthreads();
  for (int i = t; i < kNB; i += 256) {
    int c = h[i];
    if (c) atomicAdd(gbhist + i, c);
  }
}

__global__ void __launch_bounds__(256) k_bprefix(const int* __restrict__ gbhist,
                                                 int* __restrict__ bucketbase,
                                                 int* __restrict__ gcursor,
                                                 int* __restrict__ rowptr) {
  __shared__ int sh[256];
  int t = threadIdx.x;
  int v = (t < kNB) ? gbhist[t] : 0;
  sh[t] = v;
  __syncthreads();
  for (int off = 1; off < 256; off <<= 1) {
    int a = (t >= off) ? sh[t - off] : 0;
    __syncthreads();
    sh[t] += a;
    __syncthreads();
  }
  int excl = sh[t] - v;
  if (t <= kNB) bucketbase[t] = excl;
  if (t < kNB) gcursor[t] = excl;
  if (t == 0) rowptr[kN] = kE;
}

__global__ void __launch_bounds__(256) k_part1(
    const int* __restrict__ src, const int* __restrict__ dst,
    const float* __restrict__ ts, int* __restrict__ gcursor,
    unsigned long long* __restrict__ tmp) {
  __shared__ int hist[kNB];
  __shared__ int lbase[kNB];
  int t = threadIdx.x;
  for (int i = t; i < kNB; i += 256) hist[i] = 0;
  __syncthreads();
  int base = blockIdx.x * kCH;
  int bk[8];
  unsigned long long ent[8];
#pragma unroll
  for (int i = 0; i < 8; ++i) {
    int e = base + i * 256 + t;
    if (e < kE) {
      int d = dst[e];
      int b = d >> 8;
      bk[i] = b;
      unsigned lo = (unsigned)src[e] | ((unsigned)(d & 255) << 16);
      ent[i] = ((unsigned long long)(unsigned)__float_as_int(ts[e]) << 32) | lo;
      atomicAdd(&hist[b], 1);
    } else {
      bk[i] = -1;
    }
  }
  __syncthreads();
  for (int i = t; i < kNB; i += 256) {
    int c = hist[i];
    lbase[i] = c ? atomicAdd(gcursor + i, c) : 0;
  }
  __syncthreads();
  for (int i = t; i < kNB; i += 256) hist[i] = 0;
  __syncthreads();
#pragma unroll
  for (int i = 0; i < 8; ++i) {
    if (bk[i] >= 0) {
      int off = atomicAdd(&hist[bk[i]], 1);
      __builtin_nontemporal_store(ent[i], tmp + lbase[bk[i]] + off);
    }
  }
}

__global__ void __launch_bounds__(256) k_part2(
    const unsigned long long* __restrict__ tmp, const int* __restrict__ bucketbase,
    int* __restrict__ rowptr, int2* __restrict__ csr) {
  __shared__ int cnt[256];
  __shared__ int sh[256];
  __shared__ int cur[256];
  int b = blockIdx.x;
  int t = threadIdx.x;
  int lo = bucketbase[b], hi = bucketbase[b + 1];
  int nnode = kN - b * 256;
  nnode = nnode < 256 ? nnode : 256;
  cnt[t] = 0;
  __syncthreads();
  for (int p = lo + t; p < hi; p += 256) {
    unsigned long long e = __builtin_nontemporal_load(tmp + p);
    atomicAdd(&cnt[((unsigned)e >> 16) & 255], 1);
  }
  __syncthreads();
  int v = cnt[t];
  sh[t] = v;
  __syncthreads();
  for (int off = 1; off < 256; off <<= 1) {
    int a = (t >= off) ? sh[t - off] : 0;
    __syncthreads();
    sh[t] += a;
    __syncthreads();
  }
  int nodebase = lo + sh[t] - v;
  if (t < nnode) rowptr[b * 256 + t] = nodebase;
  cur[t] = nodebase;
  __syncthreads();
  for (int p = lo + t; p < hi; p += 256) {
    unsigned long long e = __builtin_nontemporal_load(tmp + p);
    unsigned elo = (unsigned)e;
    int pos = atomicAdd(&cur[(elo >> 16) & 255], 1);
    csr[pos] = make_int2((int)(elo & 0xffffu), (int)(unsigned)(e >> 32));
  }
}

// ---------- time encoding gather + zero pad: hb16[n,128..143]=t_enc, [144..159]=0 ----------
__global__ void __launch_bounds__(256) k_time_gather(
    const int* __restrict__ rowptr, const int2* __restrict__ csr,
    const float* __restrict__ tw, const float* __restrict__ tb,
    unsigned short* __restrict__ hb) {
  int n = blockIdx.x * 4 + (threadIdx.x >> 6);
  if (n >= kN) return;
  int lane = threadIdx.x & 63;
  int j = lane & 15, grp = lane >> 4;
  float w = tw[j], b = tb[j];
  int lo = rowptr[n], hi = rowptr[n + 1];
  float s = 0.f;
  for (int p = lo + grp; p < hi; p += 4) {
    s += cosf(__int_as_float(csr[p].y) * w + b);
  }
  s += __shfl_xor(s, 16);
  s += __shfl_xor(s, 32);
  if (grp == 0) hb[(size_t)n * 160 + 128 + j] = f2bf(s);
  if (grp == 1) hb[(size_t)n * 160 + 144 + j] = 0;
}

// ---------- MFMA projection: hb16[n,0..127] = bf16(x @ pw^T + bias), x read as f32 ----------
__global__ void __launch_bounds__(256) k_mfma_proj(
    const float* __restrict__ x, const unsigned short* __restrict__ wb,
    const float* __restrict__ bias, unsigned short* __restrict__ outb) {
  int n0 = blockIdx.x * 16;
  int wv = threadIdx.x >> 6, l = threadIdx.x & 63;
  int lr = l & 15, lk = l >> 4;
  const int K = 128;
  int jt0 = 2 * wv, jt1 = 2 * wv + 1;
  const float* arow = x + (size_t)(n0 + lr) * K + lk * 8;
  const unsigned short* brow0 = wb + (size_t)(jt0 * 16 + lr) * K + lk * 8;
  const unsigned short* brow1 = wb + (size_t)(jt1 * 16 + lr) * K + lk * 8;
  f32x4 acc0 = {0.f, 0.f, 0.f, 0.f}, acc1 = {0.f, 0.f, 0.f, 0.f};
#pragma unroll
  for (int c = 0; c < 4; ++c) {
    float4 alo = *(const float4*)(arow + c * 32);
    float4 ahi = *(const float4*)(arow + c * 32 + 4);
    bf16x8 a;
    a[0] = (short)f2bf(alo.x); a[1] = (short)f2bf(alo.y);
    a[2] = (short)f2bf(alo.z); a[3] = (short)f2bf(alo.w);
    a[4] = (short)f2bf(ahi.x); a[5] = (short)f2bf(ahi.y);
    a[6] = (short)f2bf(ahi.z); a[7] = (short)f2bf(ahi.w);
    acc0 = __builtin_amdgcn_mfma_f32_16x16x32_bf16(a, *(const bf16x8*)(brow0 + c * 32), acc0, 0, 0, 0);
    acc1 = __builtin_amdgcn_mfma_f32_16x16x32_bf16(a, *(const bf16x8*)(brow1 + c * 32), acc1, 0, 0, 0);
  }
  int j0 = jt0 * 16 + lr, j1 = jt1 * 16 + lr;
  float bb0 = bias[j0], bb1 = bias[j1];
#pragma unroll
  for (int r = 0; r < 4; ++r) {
    int node = n0 + lk * 4 + r;
    outb[(size_t)node * 160 + j0] = f2bf(acc0[r] + bb0);
    outb[(size_t)node * 160 + j1] = f2bf(acc1[r] + bb1);
  }
}

// ---------- MFMA xh = h @ W^T (bf16 in/out) fused with att dots ----------
__global__ void __launch_bounds__(256) k_mfma_xh_att(
    const unsigned short* __restrict__ hb, int K,
    const unsigned short* __restrict__ wb,
    const float* __restrict__ att_s, const float* __restrict__ att_d,
    unsigned short* __restrict__ xh, float* __restrict__ a_src,
    float* __restrict__ a_dst) {
  int n0 = blockIdx.x * 16;
  int wv = threadIdx.x >> 6, l = threadIdx.x & 63;
  int lr = l & 15, lk = l >> 4;
  int jt0 = 2 * wv, jt1 = 2 * wv + 1;
  const unsigned short* arow = hb + (size_t)(n0 + lr) * K + lk * 8;
  const unsigned short* brow0 = wb + (size_t)(jt0 * 16 + lr) * K + lk * 8;
  const unsigned short* brow1 = wb + (size_t)(jt1 * 16 + lr) * K + lk * 8;
  f32x4 acc0 = {0.f, 0.f, 0.f, 0.f}, acc1 = {0.f, 0.f, 0.f, 0.f};
  int nch = K >> 5;
  for (int c = 0; c < nch; ++c) {
    bf16x8 a = *(const bf16x8*)(arow + c * 32);
    acc0 = __builtin_amdgcn_mfma_f32_16x16x32_bf16(a, *(const bf16x8*)(brow0 + c * 32), acc0, 0, 0, 0);
    acc1 = __builtin_amdgcn_mfma_f32_16x16x32_bf16(a, *(const bf16x8*)(brow1 + c * 32), acc1, 0, 0, 0);
  }
  int j0 = jt0 * 16 + lr, j1 = jt1 * 16 + lr;
  float as0 = att_s[j0], as1 = att_s[j1];
  float ad0 = att_d[j0], ad1 = att_d[j1];
#pragma unroll
  for (int r = 0; r < 4; ++r) {
    int node = n0 + lk * 4 + r;
    float d0 = acc0[r], d1 = acc1[r];
    xh[(size_t)node * 128 + j0] = f2bf(d0);
    xh[(size_t)node * 128 + j1] = f2bf(d1);
    float vs = d0 * as0 + d1 * as1;
    float vd = d0 * ad0 + d1 * ad1;
    vs += __shfl_xor(vs, 1); vs += __shfl_xor(vs, 2);
    vs += __shfl_xor(vs, 4); vs += __shfl_xor(vs, 8);
    vd += __shfl_xor(vd, 1); vd += __shfl_xor(vd, 2);
    vd += __shfl_xor(vd, 4); vd += __shfl_xor(vd, 8);
    if (lr == 0) {
      a_src[node * 4 + wv] = vs;
      a_dst[node * 4 + wv] = vd;
    }
  }
}

// ---------- GAT: exact softmax without max shift + bias + LN + ReLU, bf16 out ----------
__global__ void __launch_bounds__(256) k_gat_agg(
    const unsigned short* __restrict__ xh, const float* __restrict__ a_src,
    const float* __restrict__ a_dst,
    const int* __restrict__ rowptr, const int2* __restrict__ csr,
    const float* __restrict__ gb, const float* __restrict__ lw,
    const float* __restrict__ lb, unsigned short* __restrict__ outb) {
  int n = blockIdx.x * 4 + (threadIdx.x >> 6);
  if (n >= kN) return;
  int lane = threadIdx.x & 63;
  int eg = lane >> 4;         // edge group (0..3)
  int li = lane & 15;         // lane-in-group; channels li*8..+7
  int hd = li >> 2;           // head of this lane's channels
  float ad = a_dst[n * 4 + hd];
  const int* csrx = (const int*)csr;  // .x at even dwords

  float den = 0.f;
  float a0 = 0.f, a1 = 0.f, a2 = 0.f, a3 = 0.f, a4 = 0.f, a5 = 0.f, a6 = 0.f, a7 = 0.f;

  if (eg == 0) {
    float w_self = __expf(leaky(a_src[n * 4 + hd] + ad));
    den = w_self;
    uint4 u = ((const uint4*)(xh + (size_t)n * 128))[li];
    a0 = w_self * bflo(u.x); a1 = w_self * bfhi(u.x);
    a2 = w_self * bflo(u.y); a3 = w_self * bfhi(u.y);
    a4 = w_self * bflo(u.z); a5 = w_self * bfhi(u.z);
    a6 = w_self * bflo(u.w); a7 = w_self * bfhi(u.w);
  }

  int lo = rowptr[n], hi = rowptr[n + 1];
#pragma unroll 4
  for (int p = lo; p < hi; p += 4) {
    int e = p + eg;
    if (e < hi) {
      int s = __builtin_nontemporal_load(csrx + 2 * (size_t)e);
      float wv = __expf(leaky(a_src[s * 4 + hd] + ad));
      uint4 u = ((const uint4*)(xh + (size_t)s * 128))[li];
      den += wv;
      a0 += wv * bflo(u.x); a1 += wv * bfhi(u.x);
      a2 += wv * bflo(u.y); a3 += wv * bfhi(u.y);
      a4 += wv * bflo(u.z); a5 += wv * bfhi(u.z);
      a6 += wv * bflo(u.w); a7 += wv * bfhi(u.w);
    }
  }

#pragma unroll
  for (int off = 16; off <= 32; off <<= 1) {
    den += __shfl_xor(den, off);
    a0 += __shfl_xor(a0, off); a1 += __shfl_xor(a1, off);
    a2 += __shfl_xor(a2, off); a3 += __shfl_xor(a3, off);
    a4 += __shfl_xor(a4, off); a5 += __shfl_xor(a5, off);
    a6 += __shfl_xor(a6, off); a7 += __shfl_xor(a7, off);
  }

  float inv = 1.f / den;
  int c0 = li * 8;
  float4 gbl = *(const float4*)(gb + c0);
  float4 gbh = *(const float4*)(gb + c0 + 4);
  float v0 = a0 * inv + gbl.x, v1 = a1 * inv + gbl.y;
  float v2 = a2 * inv + gbl.z, v3 = a3 * inv + gbl.w;
  float v4 = a4 * inv + gbh.x, v5 = a5 * inv + gbh.y;
  float v6 = a6 * inv + gbh.z, v7 = a7 * inv + gbh.w;
  float s = v0 + v1 + v2 + v3 + v4 + v5 + v6 + v7;
  float sq = v0*v0 + v1*v1 + v2*v2 + v3*v3 + v4*v4 + v5*v5 + v6*v6 + v7*v7;
#pragma unroll
  for (int off = 1; off <= 8; off <<= 1) {
    s += __shfl_xor(s, off);
    sq += __shfl_xor(sq, off);
  }
  float mean = s * (1.f / 128.f);
  float var = sq * (1.f / 128.f) - mean * mean;
  float rs = rsqrtf(var + LN_EPS);
  if (eg == 0) {
    float4 lwl = *(const float4*)(lw + c0), lwh = *(const float4*)(lw + c0 + 4);
    float4 lbl = *(const float4*)(lb + c0), lbh = *(const float4*)(lb + c0 + 4);
    float y0 = fmaxf((v0 - mean) * rs * lwl.x + lbl.x, 0.f);
    float y1 = fmaxf((v1 - mean) * rs * lwl.y + lbl.y, 0.f);
    float y2 = fmaxf((v2 - mean) * rs * lwl.z + lbl.z, 0.f);
    float y3 = fmaxf((v3 - mean) * rs * lwl.w + lbl.w, 0.f);
    float y4 = fmaxf((v4 - mean) * rs * lwh.x + lbh.x, 0.f);
    float y5 = fmaxf((v5 - mean) * rs * lwh.y + lbh.y, 0.f);
    float y6 = fmaxf((v6 - mean) * rs * lwh.z + lbh.z, 0.f);
    float y7 = fmaxf((v7 - mean) * rs * lwh.w + lbh.w, 0.f);
    uv4 o;
    o.x = (unsigned)f2bf(y0) | ((unsigned)f2bf(y1) << 16);
    o.y = (unsigned)f2bf(y2) | ((unsigned)f2bf(y3) << 16);
    o.z = (unsigned)f2bf(y4) | ((unsigned)f2bf(y5) << 16);
    o.w = (unsigned)f2bf(y6) | ((unsigned)f2bf(y7) << 16);
    __builtin_nontemporal_store(o, (uv4*)(outb + (size_t)n * 128 + c0));
  }
}

// ---------- pooling stage 1 (bf16 input): 64 groups x 16 chunks ----------
__global__ void __launch_bounds__(128) k_pool1(
    const unsigned short* __restrict__ h, const int* __restrict__ batch,
    float* __restrict__ psum, float* __restrict__ pmax) {
  int g = blockIdx.x >> 4, chunk = blockIdx.x & (kPOOLC - 1);
  int c = threadIdx.x;  // 128 channels
  int lo, hi;
  { int a = 0, b = kN; while (a < b) { int m = (a + b) >> 1; if (batch[m] < g) a = m + 1; else b = m; } lo = a; }
  { int a = 0, b = kN; while (a < b) { int m = (a + b) >> 1; if (batch[m] < g + 1) a = m + 1; else b = m; } hi = a; }
  int len = hi - lo;
  int c0 = lo + (int)(((long long)len * chunk) / kPOOLC);
  int c1 = lo + (int)(((long long)len * (chunk + 1)) / kPOOLC);
  float s = 0.f, mx = -INFINITY;
  for (int n = c0; n < c1; ++n) {
    unsigned short hv = __builtin_nontemporal_load(h + (size_t)n * 128 + c);
    float v = __uint_as_float(((unsigned)hv) << 16);
    s += v;
    mx = fmaxf(mx, v);
  }
  psum[(size_t)blockIdx.x * 128 + c] = s;
  pmax[(size_t)blockIdx.x * 128 + c] = mx;
}

// ---------- pooling stage 2 + classifier (fused; one block per group) ----------
__global__ void __launch_bounds__(128) k_pool2_cls(
    const float* __restrict__ psum, const float* __restrict__ pmax,
    const int* __restrict__ batch,
    const float* __restrict__ w1t, const float* __restrict__ b1,
    const float* __restrict__ w2, const float* __restrict__ b2,
    float* __restrict__ out) {
  __shared__ float row[256];
  __shared__ float o1[128];
  int g = blockIdx.x;
  int c = threadIdx.x;
  int lo, hi;
  { int a = 0, b = kN; while (a < b) { int m = (a + b) >> 1; if (batch[m] < g) a = m + 1; else b = m; } lo = a; }
  { int a = 0, b = kN; while (a < b) { int m = (a + b) >> 1; if (batch[m] < g + 1) a = m + 1; else b = m; } hi = a; }
  float s = 0.f, mx = -INFINITY;
#pragma unroll
  for (int k = 0; k < kPOOLC; ++k) {
    s += psum[(size_t)(g * kPOOLC + k) * 128 + c];
    mx = fmaxf(mx, pmax[(size_t)(g * kPOOLC + k) * 128 + c]);
  }
  int cnt = hi - lo;
  row[c] = (cnt > 0) ? s / (float)cnt : 0.f;
  row[c + 128] = mx;
  __syncthreads();
  float t = b1[c];
  for (int k = 0; k < 256; ++k) t += row[k] * w1t[k * 128 + c];
  o1[c] = fmaxf(t, 0.f);
  __syncthreads();
  if (c < 2) {
    float r = b2[c];
    for (int j = 0; j < 128; ++j) r += o1[j] * w2[c * 128 + j];
    out[g * 2 + c] = r;
  }
}

extern "C" void kernel_launch(void* const* d_in, const int* in_sizes, int n_in,
                              void* d_out, int out_size, void* d_ws, size_t ws_size,
                              hipStream_t stream) {
  const float* x      = (const float*)d_in[0];
  const int*   ei     = (const int*)d_in[1];
  const float* ts     = (const float*)d_in[2];
  const int*   batch  = (const int*)d_in[3];
  const float* time_w = (const float*)d_in[4];
  const float* time_b = (const float*)d_in[5];
  const float* proj_w = (const float*)d_in[6];
  const float* proj_b = (const float*)d_in[7];
  const float* g0w    = (const float*)d_in[8];
  const float* as0    = (const float*)d_in[9];
  const float* ad0    = (const float*)d_in[10];
  const float* g0b    = (const float*)d_in[11];
  const float* ln0w   = (const float*)d_in[12];
  const float* ln0b   = (const float*)d_in[13];
  const float* g1w    = (const float*)d_in[14];
  const float* as1    = (const float*)d_in[15];
  const float* ad1    = (const float*)d_in[16];
  const float* g1b    = (const float*)d_in[17];
  const float* ln1w   = (const float*)d_in[18];
  const float* ln1b   = (const float*)d_in[19];
  const float* c1w    = (const float*)d_in[20];
  const float* c1b    = (const float*)d_in[21];
  const float* c2w    = (const float*)d_in[22];
  const float* c2b    = (const float*)d_in[23];
  float* out = (float*)d_out;

  const int* src = ei;
  const int* dst = ei + kE;

  // ---- workspace layout (bytes; all large regions 16B-aligned) ----
  char* p = (char*)d_ws;
  unsigned short* xh   = (unsigned short*)p; p += (size_t)kN * 128 * 2;
  unsigned short* hb16 = (unsigned short*)p; p += (size_t)kN * 160 * 2;  // layer-0 input (padded K=160)
  unsigned short* h1b16= (unsigned short*)p; p += (size_t)kN * 128 * 2;  // gat outputs (bf16)
  float* a_src = (float*)p; p += (size_t)kN * 4 * 4;
  float* a_dst = (float*)p; p += (size_t)kN * 4 * 4;
  unsigned short* pwb = (unsigned short*)p; p += 128 * 128 * 2;
  unsigned short* w0b = (unsigned short*)p; p += 128 * 160 * 2;
  unsigned short* w1b = (unsigned short*)p; p += 128 * 128 * 2;
  float* c1T = (float*)p; p += 256 * 128 * 4;
  int2* csr = (int2*)p; p += (size_t)kE * 8;
  unsigned long long* tmp = (unsigned long long*)p; p += (size_t)kE * 8;
  float* psum = (float*)p; p += (size_t)kG * kPOOLC * 128 * 4;
  float* pmax = (float*)p; p += (size_t)kG * kPOOLC * 128 * 4;
  int* rowptr = (int*)p; p += (kN + 1) * 4;
  int* gbhist = (int*)p; p += kNB * 4;
  int* bucketbase = (int*)p; p += (kNB + 1) * 4;
  int* gcursor = (int*)p; p += kNB * 4;

  // ---- prep (weights + gbhist zero) ----
  k_prep<<<(kP4 + 255) / 256, 256, 0, stream>>>(c1w, c1T, proj_w, pwb, g0w, w0b,
                                                g1w, w1b, gbhist);

  // ---- CSR build: bucket partition ----
  k_part0<<<kPB, 256, 0, stream>>>(dst, gbhist);
  k_bprefix<<<1, 256, 0, stream>>>(gbhist, bucketbase, gcursor, rowptr);
  k_part1<<<kPB, 256, 0, stream>>>(src, dst, ts, gcursor, tmp);
  k_part2<<<kNB, 256, 0, stream>>>(tmp, bucketbase, rowptr, csr);

  // ---- projection (MFMA, reads f32 x) + time encoding (incl. zero pad) ----
  k_mfma_proj<<<kN / 16, 256, 0, stream>>>(x, pwb, proj_b, hb16);
  k_time_gather<<<kN / 4, 256, 0, stream>>>(rowptr, csr, time_w, time_b, hb16);

  // ---- GAT layer 0 ----
  k_mfma_xh_att<<<kN / 16, 256, 0, stream>>>(hb16, 160, w0b, as0, ad0, xh, a_src, a_dst);
  k_gat_agg<<<kN / 4, 256, 0, stream>>>(xh, a_src, a_dst, rowptr, csr,
                                        g0b, ln0w, ln0b, h1b16);

  // ---- GAT layer 1 ----
  k_mfma_xh_att<<<kN / 16, 256, 0, stream>>>(h1b16, 128, w1b, as1, ad1, xh, a_src, a_dst);
  k_gat_agg<<<kN / 4, 256, 0, stream>>>(xh, a_src, a_dst, rowptr, csr,
                                        g1b, ln1w, ln1b, h1b16);

  // ---- pooling + classifier ----
  k_pool1<<<kG * kPOOLC, 128, 0, stream>>>(h1b16, batch, psum, pmax);
  k_pool2_cls<<<kG, 128, 0, stream>>>(psum, pmax, batch, c1T, c1b, c2w, c2b, out);
}

// Round 13
// 270.769 us; speedup vs baseline: 1.1684x; 1.1684x over previous
//
#include <hip/hip_runtime.h>
#include <math.h>

// ---- problem constants ----
static constexpr int kN     = 40000;
static constexpr int kE     = 1000000;
static constexpr int kTDIM  = 16;
static constexpr int kG     = 64;
static constexpr int kPOOLC = 16;             // pooling chunks per group
static constexpr int kNB    = (kN + 255) / 256;   // 157 dst buckets (256 nodes each)
static constexpr int kCH    = 2048;               // edges per partition block
static constexpr int kPB    = (kE + kCH - 1) / kCH;  // 489 partition blocks
#define LN_EPS 1e-5f
#define NEG_SLOPE 0.2f

typedef __attribute__((ext_vector_type(8))) short bf16x8;
typedef __attribute__((ext_vector_type(4))) float f32x4;

__device__ __forceinline__ float leaky(float v) {
  return fmaxf(v, NEG_SLOPE * v);
}

// round-to-nearest-even f32 -> bf16 (as ushort)
__device__ __forceinline__ unsigned short f2bf(float f) {
  unsigned u = __float_as_uint(f);
  unsigned r = u + 0x7fffu + ((u >> 16) & 1u);
  return (unsigned short)(r >> 16);
}
__device__ __forceinline__ float bflo(unsigned u) { return __uint_as_float(u << 16); }
__device__ __forceinline__ float bfhi(unsigned u) { return __uint_as_float(u & 0xffff0000u); }

// ---------- prep: classifier transpose + weight bf16 conversions + gbhist zero ----------
static constexpr int kP0 = 256 * 128;          // c1T
static constexpr int kP1 = kP0 + 128 * 128;    // pwb
static constexpr int kP2 = kP1 + 128 * 160;    // w0b (K padded 144->160)
static constexpr int kP3 = kP2 + 128 * 128;    // w1b
static constexpr int kP4 = kP3 + kNB;          // gbhist zero
__global__ void __launch_bounds__(256) k_prep(
    const float* __restrict__ c1w, float* __restrict__ c1T,
    const float* __restrict__ pw, unsigned short* __restrict__ pwb,
    const float* __restrict__ g0w, unsigned short* __restrict__ w0b,
    const float* __restrict__ g1w, unsigned short* __restrict__ w1b,
    int* __restrict__ gbhist) {
  int idx = blockIdx.x * 256 + threadIdx.x;
  if (idx < kP0) {
    int j = idx / 256, k = idx - j * 256;
    c1T[k * 128 + j] = c1w[idx];
  } else if (idx < kP1) {
    int i = idx - kP0;
    pwb[i] = f2bf(pw[i]);
  } else if (idx < kP2) {
    int i = idx - kP1;
    int j = i / 160, k = i - j * 160;
    w0b[i] = (k < 144) ? f2bf(g0w[j * 144 + k]) : (unsigned short)0;
  } else if (idx < kP3) {
    int i = idx - kP2;
    w1b[i] = f2bf(g1w[i]);
  } else if (idx < kP4) {
    gbhist[idx - kP3] = 0;
  }
}

// ---------- CSR build: 2-level bucket partition ----------
__global__ void __launch_bounds__(256) k_part0(const int* __restrict__ dst,
                                               int* __restrict__ gbhist) {
  __shared__ int h[kNB];
  int t = threadIdx.x;
  for (int i = t; i < kNB; i += 256) h[i] = 0;
  __syncthreads();
  int base = blockIdx.x * kCH;
#pragma unroll
  for (int i = 0; i < kCH / 256; ++i) {
    int e = base + i * 256 + t;
    if (e < kE) atomicAdd(&h[dst[e] >> 8], 1);
  }
  __syncthreads();
  for (int i = t; i < kNB; i += 256) {
    int c = h[i];
    if (c) atomicAdd(gbhist + i, c);
  }
}

__global__ void __launch_bounds__(256) k_bprefix(const int* __restrict__ gbhist,
                                                 int* __restrict__ bucketbase,
                                                 int* __restrict__ gcursor,
                                                 int* __restrict__ rowptr) {
  __shared__ int sh[256];
  int t = threadIdx.x;
  int v = (t < kNB) ? gbhist[t] : 0;
  sh[t] = v;
  __syncthreads();
  for (int off = 1; off < 256; off <<= 1) {
    int a = (t >= off) ? sh[t - off] : 0;
    __syncthreads();
    sh[t] += a;
    __syncthreads();
  }
  int excl = sh[t] - v;
  if (t <= kNB) bucketbase[t] = excl;
  if (t < kNB) gcursor[t] = excl;
  if (t == 0) rowptr[kN] = kE;
}

__global__ void __launch_bounds__(256) k_part1(
    const int* __restrict__ src, const int* __restrict__ dst,
    const float* __restrict__ ts, int* __restrict__ gcursor,
    unsigned long long* __restrict__ tmp) {
  __shared__ int hist[kNB];
  __shared__ int lbase[kNB];
  int t = threadIdx.x;
  for (int i = t; i < kNB; i += 256) hist[i] = 0;
  __syncthreads();
  int base = blockIdx.x * kCH;
  int bk[8];
  unsigned long long ent[8];
#pragma unroll
  for (int i = 0; i < 8; ++i) {
    int e = base + i * 256 + t;
    if (e < kE) {
      int d = dst[e];
      int b = d >> 8;
      bk[i] = b;
      unsigned lo = (unsigned)src[e] | ((unsigned)(d & 255) << 16);
      ent[i] = ((unsigned long long)(unsigned)__float_as_int(ts[e]) << 32) | lo;
      atomicAdd(&hist[b], 1);
    } else {
      bk[i] = -1;
    }
  }
  __syncthreads();
  for (int i = t; i < kNB; i += 256) {
    int c = hist[i];
    lbase[i] = c ? atomicAdd(gcursor + i, c) : 0;
  }
  __syncthreads();
  for (int i = t; i < kNB; i += 256) hist[i] = 0;
  __syncthreads();
#pragma unroll
  for (int i = 0; i < 8; ++i) {
    if (bk[i] >= 0) {
      int off = atomicAdd(&hist[bk[i]], 1);
      tmp[lbase[bk[i]] + off] = ent[i];
    }
  }
}

__global__ void __launch_bounds__(256) k_part2(
    const unsigned long long* __restrict__ tmp, const int* __restrict__ bucketbase,
    int* __restrict__ rowptr, int2* __restrict__ csr) {
  __shared__ int cnt[256];
  __shared__ int sh[256];
  __shared__ int cur[256];
  int b = blockIdx.x;
  int t = threadIdx.x;
  int lo = bucketbase[b], hi = bucketbase[b + 1];
  int nnode = kN - b * 256;
  nnode = nnode < 256 ? nnode : 256;
  cnt[t] = 0;
  __syncthreads();
  for (int p = lo + t; p < hi; p += 256)
    atomicAdd(&cnt[((unsigned)tmp[p] >> 16) & 255], 1);
  __syncthreads();
  int v = cnt[t];
  sh[t] = v;
  __syncthreads();
  for (int off = 1; off < 256; off <<= 1) {
    int a = (t >= off) ? sh[t - off] : 0;
    __syncthreads();
    sh[t] += a;
    __syncthreads();
  }
  int nodebase = lo + sh[t] - v;
  if (t < nnode) rowptr[b * 256 + t] = nodebase;
  cur[t] = nodebase;
  __syncthreads();
  for (int p = lo + t; p < hi; p += 256) {
    unsigned long long e = tmp[p];
    unsigned elo = (unsigned)e;
    int pos = atomicAdd(&cur[(elo >> 16) & 255], 1);
    csr[pos] = make_int2((int)(elo & 0xffffu), (int)(unsigned)(e >> 32));
  }
}

// ---------- time encoding gather + zero pad: hb16[n,128..143]=t_enc, [144..159]=0 ----------
__global__ void __launch_bounds__(256) k_time_gather(
    const int* __restrict__ rowptr, const int2* __restrict__ csr,
    const float* __restrict__ tw, const float* __restrict__ tb,
    unsigned short* __restrict__ hb) {
  int n = blockIdx.x * 4 + (threadIdx.x >> 6);
  if (n >= kN) return;
  int lane = threadIdx.x & 63;
  int j = lane & 15, grp = lane >> 4;
  float w = tw[j], b = tb[j];
  int lo = rowptr[n], hi = rowptr[n + 1];
  float s = 0.f;
  for (int p = lo + grp; p < hi; p += 4) {
    s += cosf(__int_as_float(csr[p].y) * w + b);
  }
  s += __shfl_xor(s, 16);
  s += __shfl_xor(s, 32);
  if (grp == 0) hb[(size_t)n * 160 + 128 + j] = f2bf(s);
  if (grp == 1) hb[(size_t)n * 160 + 144 + j] = 0;
}

// ---------- MFMA projection: hb16[n,0..127] = bf16(x @ pw^T + bias), x read as f32 ----------
__global__ void __launch_bounds__(256) k_mfma_proj(
    const float* __restrict__ x, const unsigned short* __restrict__ wb,
    const float* __restrict__ bias, unsigned short* __restrict__ outb) {
  int n0 = blockIdx.x * 16;
  int wv = threadIdx.x >> 6, l = threadIdx.x & 63;
  int lr = l & 15, lk = l >> 4;
  const int K = 128;
  int jt0 = 2 * wv, jt1 = 2 * wv + 1;
  const float* arow = x + (size_t)(n0 + lr) * K + lk * 8;
  const unsigned short* brow0 = wb + (size_t)(jt0 * 16 + lr) * K + lk * 8;
  const unsigned short* brow1 = wb + (size_t)(jt1 * 16 + lr) * K + lk * 8;
  f32x4 acc0 = {0.f, 0.f, 0.f, 0.f}, acc1 = {0.f, 0.f, 0.f, 0.f};
#pragma unroll
  for (int c = 0; c < 4; ++c) {
    float4 alo = *(const float4*)(arow + c * 32);
    float4 ahi = *(const float4*)(arow + c * 32 + 4);
    bf16x8 a;
    a[0] = (short)f2bf(alo.x); a[1] = (short)f2bf(alo.y);
    a[2] = (short)f2bf(alo.z); a[3] = (short)f2bf(alo.w);
    a[4] = (short)f2bf(ahi.x); a[5] = (short)f2bf(ahi.y);
    a[6] = (short)f2bf(ahi.z); a[7] = (short)f2bf(ahi.w);
    acc0 = __builtin_amdgcn_mfma_f32_16x16x32_bf16(a, *(const bf16x8*)(brow0 + c * 32), acc0, 0, 0, 0);
    acc1 = __builtin_amdgcn_mfma_f32_16x16x32_bf16(a, *(const bf16x8*)(brow1 + c * 32), acc1, 0, 0, 0);
  }
  int j0 = jt0 * 16 + lr, j1 = jt1 * 16 + lr;
  float bb0 = bias[j0], bb1 = bias[j1];
#pragma unroll
  for (int r = 0; r < 4; ++r) {
    int node = n0 + lk * 4 + r;
    outb[(size_t)node * 160 + j0] = f2bf(acc0[r] + bb0);
    outb[(size_t)node * 160 + j1] = f2bf(acc1[r] + bb1);
  }
}

// ---------- MFMA xh = h @ W^T (bf16 in/out) fused with att dots ----------
__global__ void __launch_bounds__(256) k_mfma_xh_att(
    const unsigned short* __restrict__ hb, int K,
    const unsigned short* __restrict__ wb,
    const float* __restrict__ att_s, const float* __restrict__ att_d,
    unsigned short* __restrict__ xh, float* __restrict__ a_src,
    float* __restrict__ a_dst) {
  int n0 = blockIdx.x * 16;
  int wv = threadIdx.x >> 6, l = threadIdx.x & 63;
  int lr = l & 15, lk = l >> 4;
  int jt0 = 2 * wv, jt1 = 2 * wv + 1;
  const unsigned short* arow = hb + (size_t)(n0 + lr) * K + lk * 8;
  const unsigned short* brow0 = wb + (size_t)(jt0 * 16 + lr) * K + lk * 8;
  const unsigned short* brow1 = wb + (size_t)(jt1 * 16 + lr) * K + lk * 8;
  f32x4 acc0 = {0.f, 0.f, 0.f, 0.f}, acc1 = {0.f, 0.f, 0.f, 0.f};
  int nch = K >> 5;
  for (int c = 0; c < nch; ++c) {
    bf16x8 a = *(const bf16x8*)(arow + c * 32);
    acc0 = __builtin_amdgcn_mfma_f32_16x16x32_bf16(a, *(const bf16x8*)(brow0 + c * 32), acc0, 0, 0, 0);
    acc1 = __builtin_amdgcn_mfma_f32_16x16x32_bf16(a, *(const bf16x8*)(brow1 + c * 32), acc1, 0, 0, 0);
  }
  int j0 = jt0 * 16 + lr, j1 = jt1 * 16 + lr;
  float as0 = att_s[j0], as1 = att_s[j1];
  float ad0 = att_d[j0], ad1 = att_d[j1];
#pragma unroll
  for (int r = 0; r < 4; ++r) {
    int node = n0 + lk * 4 + r;
    float d0 = acc0[r], d1 = acc1[r];
    xh[(size_t)node * 128 + j0] = f2bf(d0);
    xh[(size_t)node * 128 + j1] = f2bf(d1);
    float vs = d0 * as0 + d1 * as1;
    float vd = d0 * ad0 + d1 * ad1;
    vs += __shfl_xor(vs, 1); vs += __shfl_xor(vs, 2);
    vs += __shfl_xor(vs, 4); vs += __shfl_xor(vs, 8);
    vd += __shfl_xor(vd, 1); vd += __shfl_xor(vd, 2);
    vd += __shfl_xor(vd, 4); vd += __shfl_xor(vd, 8);
    if (lr == 0) {
      a_src[node * 4 + wv] = vs;
      a_dst[node * 4 + wv] = vd;
    }
  }
}

// ---------- GAT: exact softmax (no max shift) + bias + LN + ReLU, bf16 out ----------
// one wave per node; 16 lanes per edge (8 channels each), 4 edges per batch,
// 2-deep software pipeline: batch i+1's csr/a_src/xh loads issue before
// batch i is consumed.
__global__ void __launch_bounds__(256) k_gat_agg(
    const unsigned short* __restrict__ xh, const float* __restrict__ a_src,
    const float* __restrict__ a_dst,
    const int* __restrict__ rowptr, const int2* __restrict__ csr,
    const float* __restrict__ gb, const float* __restrict__ lw,
    const float* __restrict__ lb, unsigned short* __restrict__ outb) {
  int n = blockIdx.x * 4 + (threadIdx.x >> 6);
  if (n >= kN) return;
  int lane = threadIdx.x & 63;
  int eg = lane >> 4;         // edge group (0..3)
  int li = lane & 15;         // lane-in-group; channels li*8..+7
  int hd = li >> 2;           // head of this lane's channels
  float ad = a_dst[n * 4 + hd];
  const int* csrx = (const int*)csr;  // .x at even dwords

  float den = 0.f;
  float a0 = 0.f, a1 = 0.f, a2 = 0.f, a3 = 0.f, a4 = 0.f, a5 = 0.f, a6 = 0.f, a7 = 0.f;

  // self-loop (group 0 only)
  if (eg == 0) {
    float w_self = __expf(leaky(a_src[n * 4 + hd] + ad));
    den = w_self;
    uint4 u = ((const uint4*)(xh + (size_t)n * 128))[li];
    a0 = w_self * bflo(u.x); a1 = w_self * bfhi(u.x);
    a2 = w_self * bflo(u.y); a3 = w_self * bfhi(u.y);
    a4 = w_self * bflo(u.z); a5 = w_self * bfhi(u.z);
    a6 = w_self * bflo(u.w); a7 = w_self * bfhi(u.w);
  }

  int lo = rowptr[n], hi = rowptr[n + 1];
  int s_cur = -1;
  uint4 u_cur = {0, 0, 0, 0};
  float asrc_cur = 0.f;
  {
    int e = lo + eg;
    if (e < hi) {
      s_cur = csrx[2 * (size_t)e];
      u_cur = ((const uint4*)(xh + (size_t)s_cur * 128))[li];
      asrc_cur = a_src[s_cur * 4 + hd];
    }
  }
  for (int p = lo; p < hi; p += 4) {
    // issue next batch's loads
    int s_next = -1;
    uint4 u_next = {0, 0, 0, 0};
    float asrc_next = 0.f;
    int en = p + 4 + eg;
    if (en < hi) {
      s_next = csrx[2 * (size_t)en];
      u_next = ((const uint4*)(xh + (size_t)s_next * 128))[li];
      asrc_next = a_src[s_next * 4 + hd];
    }
    // consume current batch
    if (s_cur >= 0) {
      float wv = __expf(leaky(asrc_cur + ad));
      den += wv;
      a0 += wv * bflo(u_cur.x); a1 += wv * bfhi(u_cur.x);
      a2 += wv * bflo(u_cur.y); a3 += wv * bfhi(u_cur.y);
      a4 += wv * bflo(u_cur.z); a5 += wv * bfhi(u_cur.z);
      a6 += wv * bflo(u_cur.w); a7 += wv * bfhi(u_cur.w);
    }
    s_cur = s_next;
    u_cur = u_next;
    asrc_cur = asrc_next;
  }

  // cross-group combine (lanes with same li across eg): xor 16, 32
#pragma unroll
  for (int off = 16; off <= 32; off <<= 1) {
    den += __shfl_xor(den, off);
    a0 += __shfl_xor(a0, off); a1 += __shfl_xor(a1, off);
    a2 += __shfl_xor(a2, off); a3 += __shfl_xor(a3, off);
    a4 += __shfl_xor(a4, off); a5 += __shfl_xor(a5, off);
    a6 += __shfl_xor(a6, off); a7 += __shfl_xor(a7, off);
  }

  float inv = 1.f / den;
  int c0 = li * 8;
  float4 gbl = *(const float4*)(gb + c0);
  float4 gbh = *(const float4*)(gb + c0 + 4);
  float v0 = a0 * inv + gbl.x, v1 = a1 * inv + gbl.y;
  float v2 = a2 * inv + gbl.z, v3 = a3 * inv + gbl.w;
  float v4 = a4 * inv + gbh.x, v5 = a5 * inv + gbh.y;
  float v6 = a6 * inv + gbh.z, v7 = a7 * inv + gbh.w;
  float s = v0 + v1 + v2 + v3 + v4 + v5 + v6 + v7;
  float sq = v0*v0 + v1*v1 + v2*v2 + v3*v3 + v4*v4 + v5*v5 + v6*v6 + v7*v7;
#pragma unroll
  for (int off = 1; off <= 8; off <<= 1) {
    s += __shfl_xor(s, off);
    sq += __shfl_xor(sq, off);
  }
  float mean = s * (1.f / 128.f);
  float var = sq * (1.f / 128.f) - mean * mean;
  float rs = rsqrtf(var + LN_EPS);
  if (eg == 0) {
    float4 lwl = *(const float4*)(lw + c0), lwh = *(const float4*)(lw + c0 + 4);
    float4 lbl = *(const float4*)(lb + c0), lbh = *(const float4*)(lb + c0 + 4);
    float y0 = fmaxf((v0 - mean) * rs * lwl.x + lbl.x, 0.f);
    float y1 = fmaxf((v1 - mean) * rs * lwl.y + lbl.y, 0.f);
    float y2 = fmaxf((v2 - mean) * rs * lwl.z + lbl.z, 0.f);
    float y3 = fmaxf((v3 - mean) * rs * lwl.w + lbl.w, 0.f);
    float y4 = fmaxf((v4 - mean) * rs * lwh.x + lbh.x, 0.f);
    float y5 = fmaxf((v5 - mean) * rs * lwh.y + lbh.y, 0.f);
    float y6 = fmaxf((v6 - mean) * rs * lwh.z + lbh.z, 0.f);
    float y7 = fmaxf((v7 - mean) * rs * lwh.w + lbh.w, 0.f);
    uint4 o;
    o.x = (unsigned)f2bf(y0) | ((unsigned)f2bf(y1) << 16);
    o.y = (unsigned)f2bf(y2) | ((unsigned)f2bf(y3) << 16);
    o.z = (unsigned)f2bf(y4) | ((unsigned)f2bf(y5) << 16);
    o.w = (unsigned)f2bf(y6) | ((unsigned)f2bf(y7) << 16);
    *(uint4*)(outb + (size_t)n * 128 + c0) = o;
  }
}

// ---------- pooling stage 1 (bf16 input): 64 groups x 16 chunks ----------
__global__ void __launch_bounds__(128) k_pool1(
    const unsigned short* __restrict__ h, const int* __restrict__ batch,
    float* __restrict__ psum, float* __restrict__ pmax) {
  int g = blockIdx.x >> 4, chunk = blockIdx.x & (kPOOLC - 1);
  int c = threadIdx.x;  // 128 channels
  int lo, hi;
  { int a = 0, b = kN; while (a < b) { int m = (a + b) >> 1; if (batch[m] < g) a = m + 1; else b = m; } lo = a; }
  { int a = 0, b = kN; while (a < b) { int m = (a + b) >> 1; if (batch[m] < g + 1) a = m + 1; else b = m; } hi = a; }
  int len = hi - lo;
  int c0 = lo + (int)(((long long)len * chunk) / kPOOLC);
  int c1 = lo + (int)(((long long)len * (chunk + 1)) / kPOOLC);
  float s = 0.f, mx = -INFINITY;
  for (int n = c0; n < c1; ++n) {
    float v = __uint_as_float(((unsigned)h[(size_t)n * 128 + c]) << 16);
    s += v;
    mx = fmaxf(mx, v);
  }
  psum[(size_t)blockIdx.x * 128 + c] = s;
  pmax[(size_t)blockIdx.x * 128 + c] = mx;
}

// ---------- pooling stage 2 + classifier (fused; one block per group) ----------
__global__ void __launch_bounds__(128) k_pool2_cls(
    const float* __restrict__ psum, const float* __restrict__ pmax,
    const int* __restrict__ batch,
    const float* __restrict__ w1t, const float* __restrict__ b1,
    const float* __restrict__ w2, const float* __restrict__ b2,
    float* __restrict__ out) {
  __shared__ float row[256];
  __shared__ float o1[128];
  int g = blockIdx.x;
  int c = threadIdx.x;
  int lo, hi;
  { int a = 0, b = kN; while (a < b) { int m = (a + b) >> 1; if (batch[m] < g) a = m + 1; else b = m; } lo = a; }
  { int a = 0, b = kN; while (a < b) { int m = (a + b) >> 1; if (batch[m] < g + 1) a = m + 1; else b = m; } hi = a; }
  float s = 0.f, mx = -INFINITY;
#pragma unroll
  for (int k = 0; k < kPOOLC; ++k) {
    s += psum[(size_t)(g * kPOOLC + k) * 128 + c];
    mx = fmaxf(mx, pmax[(size_t)(g * kPOOLC + k) * 128 + c]);
  }
  int cnt = hi - lo;
  row[c] = (cnt > 0) ? s / (float)cnt : 0.f;
  row[c + 128] = mx;
  __syncthreads();
  float t = b1[c];
  for (int k = 0; k < 256; ++k) t += row[k] * w1t[k * 128 + c];
  o1[c] = fmaxf(t, 0.f);
  __syncthreads();
  if (c < 2) {
    float r = b2[c];
    for (int j = 0; j < 128; ++j) r += o1[j] * w2[c * 128 + j];
    out[g * 2 + c] = r;
  }
}

extern "C" void kernel_launch(void* const* d_in, const int* in_sizes, int n_in,
                              void* d_out, int out_size, void* d_ws, size_t ws_size,
                              hipStream_t stream) {
  const float* x      = (const float*)d_in[0];
  const int*   ei     = (const int*)d_in[1];
  const float* ts     = (const float*)d_in[2];
  const int*   batch  = (const int*)d_in[3];
  const float* time_w = (const float*)d_in[4];
  const float* time_b = (const float*)d_in[5];
  const float* proj_w = (const float*)d_in[6];
  const float* proj_b = (const float*)d_in[7];
  const float* g0w    = (const float*)d_in[8];
  const float* as0    = (const float*)d_in[9];
  const float* ad0    = (const float*)d_in[10];
  const float* g0b    = (const float*)d_in[11];
  const float* ln0w   = (const float*)d_in[12];
  const float* ln0b   = (const float*)d_in[13];
  const float* g1w    = (const float*)d_in[14];
  const float* as1    = (const float*)d_in[15];
  const float* ad1    = (const float*)d_in[16];
  const float* g1b    = (const float*)d_in[17];
  const float* ln1w   = (const float*)d_in[18];
  const float* ln1b   = (const float*)d_in[19];
  const float* c1w    = (const float*)d_in[20];
  const float* c1b    = (const float*)d_in[21];
  const float* c2w    = (const float*)d_in[22];
  const float* c2b    = (const float*)d_in[23];
  float* out = (float*)d_out;

  const int* src = ei;
  const int* dst = ei + kE;

  // ---- workspace layout (bytes; all large regions 16B-aligned) ----
  char* p = (char*)d_ws;
  unsigned short* xh   = (unsigned short*)p; p += (size_t)kN * 128 * 2;
  unsigned short* hb16 = (unsigned short*)p; p += (size_t)kN * 160 * 2;  // layer-0 input (padded K=160)
  unsigned short* h1b16= (unsigned short*)p; p += (size_t)kN * 128 * 2;  // gat outputs (bf16)
  float* a_src = (float*)p; p += (size_t)kN * 4 * 4;
  float* a_dst = (float*)p; p += (size_t)kN * 4 * 4;
  unsigned short* pwb = (unsigned short*)p; p += 128 * 128 * 2;
  unsigned short* w0b = (unsigned short*)p; p += 128 * 160 * 2;
  unsigned short* w1b = (unsigned short*)p; p += 128 * 128 * 2;
  float* c1T = (float*)p; p += 256 * 128 * 4;
  int2* csr = (int2*)p; p += (size_t)kE * 8;
  unsigned long long* tmp = (unsigned long long*)p; p += (size_t)kE * 8;
  float* psum = (float*)p; p += (size_t)kG * kPOOLC * 128 * 4;
  float* pmax = (float*)p; p += (size_t)kG * kPOOLC * 128 * 4;
  int* rowptr = (int*)p; p += (kN + 1) * 4;
  int* gbhist = (int*)p; p += kNB * 4;
  int* bucketbase = (int*)p; p += (kNB + 1) * 4;
  int* gcursor = (int*)p; p += kNB * 4;

  // ---- prep (weights + gbhist zero) ----
  k_prep<<<(kP4 + 255) / 256, 256, 0, stream>>>(c1w, c1T, proj_w, pwb, g0w, w0b,
                                                g1w, w1b, gbhist);

  // ---- CSR build: bucket partition ----
  k_part0<<<kPB, 256, 0, stream>>>(dst, gbhist);
  k_bprefix<<<1, 256, 0, stream>>>(gbhist, bucketbase, gcursor, rowptr);
  k_part1<<<kPB, 256, 0, stream>>>(src, dst, ts, gcursor, tmp);
  k_part2<<<kNB, 256, 0, stream>>>(tmp, bucketbase, rowptr, csr);

  // ---- projection (MFMA, reads f32 x) + time encoding (incl. zero pad) ----
  k_mfma_proj<<<kN / 16, 256, 0, stream>>>(x, pwb, proj_b, hb16);
  k_time_gather<<<kN / 4, 256, 0, stream>>>(rowptr, csr, time_w, time_b, hb16);

  // ---- GAT layer 0 ----
  k_mfma_xh_att<<<kN / 16, 256, 0, stream>>>(hb16, 160, w0b, as0, ad0, xh, a_src, a_dst);
  k_gat_agg<<<kN / 4, 256, 0, stream>>>(xh, a_src, a_dst, rowptr, csr,
                                        g0b, ln0w, ln0b, h1b16);

  // ---- GAT layer 1 ----
  k_mfma_xh_att<<<kN / 16, 256, 0, stream>>>(h1b16, 128, w1b, as1, ad1, xh, a_src, a_dst);
  k_gat_agg<<<kN / 4, 256, 0, stream>>>(xh, a_src, a_dst, rowptr, csr,
                                        g1b, ln1w, ln1b, h1b16);

  // ---- pooling + classifier ----
  k_pool1<<<kG * kPOOLC, 128, 0, stream>>>(h1b16, batch, psum, pmax);
  k_pool2_cls<<<kG, 128, 0, stream>>>(psum, pmax, batch, c1T, c1b, c2w, c2b, out);
}

// Round 14
// 268.581 us; speedup vs baseline: 1.1779x; 1.0081x over previous
//
#include <hip/hip_runtime.h>
#include <math.h>

// ---- problem constants ----
static constexpr int kN     = 40000;
static constexpr int kE     = 1000000;
static constexpr int kTDIM  = 16;
static constexpr int kG     = 64;
static constexpr int kPOOLC = 16;             // pooling chunks per group
static constexpr int kNB    = (kN + 255) / 256;   // 157 dst buckets (256 nodes each)
static constexpr int kCH    = 4096;               // edges per partition block
static constexpr int kPB    = (kE + kCH - 1) / kCH;  // 245 partition blocks
#define LN_EPS 1e-5f
#define NEG_SLOPE 0.2f

typedef __attribute__((ext_vector_type(8))) short bf16x8;
typedef __attribute__((ext_vector_type(4))) float f32x4;

__device__ __forceinline__ float leaky(float v) {
  return fmaxf(v, NEG_SLOPE * v);
}

// round-to-nearest-even f32 -> bf16 (as ushort)
__device__ __forceinline__ unsigned short f2bf(float f) {
  unsigned u = __float_as_uint(f);
  unsigned r = u + 0x7fffu + ((u >> 16) & 1u);
  return (unsigned short)(r >> 16);
}
__device__ __forceinline__ float bflo(unsigned u) { return __uint_as_float(u << 16); }
__device__ __forceinline__ float bfhi(unsigned u) { return __uint_as_float(u & 0xffff0000u); }

// ---------- fused prep: bucket hist (blocks [0,kPB)) + weight conversions ----------
static constexpr int kP0 = 256 * 128;          // c1T
static constexpr int kP1 = kP0 + 128 * 128;    // pwb
static constexpr int kP2 = kP1 + 128 * 160;    // w0b (K padded 144->160)
static constexpr int kP3 = kP2 + 128 * 128;    // w1b
static constexpr int kPREPB = (kP3 + 255) / 256;
__global__ void __launch_bounds__(256) k_prep(
    const int* __restrict__ dst, int* __restrict__ gbhist,
    const float* __restrict__ c1w, float* __restrict__ c1T,
    const float* __restrict__ pw, unsigned short* __restrict__ pwb,
    const float* __restrict__ g0w, unsigned short* __restrict__ w0b,
    const float* __restrict__ g1w, unsigned short* __restrict__ w1b) {
  int b = blockIdx.x;
  int t = threadIdx.x;
  if (b < kPB) {
    __shared__ int h[kNB];
    for (int i = t; i < kNB; i += 256) h[i] = 0;
    __syncthreads();
    int base = b * kCH;
#pragma unroll
    for (int i = 0; i < kCH / 256; ++i) {
      int e = base + i * 256 + t;
      if (e < kE) atomicAdd(&h[dst[e] >> 8], 1);
    }
    __syncthreads();
    for (int i = t; i < kNB; i += 256) {
      int c = h[i];
      if (c) atomicAdd(gbhist + i, c);
    }
    return;
  }
  int idx = (b - kPB) * 256 + t;
  if (idx < kP0) {
    int j = idx / 256, k = idx - j * 256;
    c1T[k * 128 + j] = c1w[idx];
  } else if (idx < kP1) {
    int i = idx - kP0;
    pwb[i] = f2bf(pw[i]);
  } else if (idx < kP2) {
    int i = idx - kP1;
    int j = i / 160, k = i - j * 160;
    w0b[i] = (k < 144) ? f2bf(g0w[j * 144 + k]) : (unsigned short)0;
  } else if (idx < kP3) {
    int i = idx - kP2;
    w1b[i] = f2bf(g1w[i]);
  }
}

__global__ void __launch_bounds__(256) k_bprefix(const int* __restrict__ gbhist,
                                                 int* __restrict__ bucketbase,
                                                 int* __restrict__ gcursor,
                                                 int* __restrict__ rowptr) {
  __shared__ int sh[256];
  int t = threadIdx.x;
  int v = (t < kNB) ? gbhist[t] : 0;
  sh[t] = v;
  __syncthreads();
  for (int off = 1; off < 256; off <<= 1) {
    int a = (t >= off) ? sh[t - off] : 0;
    __syncthreads();
    sh[t] += a;
    __syncthreads();
  }
  int excl = sh[t] - v;
  if (t <= kNB) bucketbase[t] = excl;
  if (t < kNB) gcursor[t] = excl;
  if (t == 0) rowptr[kN] = kE;
}

__global__ void __launch_bounds__(256) k_part1(
    const int* __restrict__ src, const int* __restrict__ dst,
    const float* __restrict__ ts, int* __restrict__ gcursor,
    unsigned long long* __restrict__ tmp) {
  __shared__ int hist[kNB];
  __shared__ int lbase[kNB];
  int t = threadIdx.x;
  for (int i = t; i < kNB; i += 256) hist[i] = 0;
  __syncthreads();
  int base = blockIdx.x * kCH;
  int bk[kCH / 256];
  unsigned long long ent[kCH / 256];
#pragma unroll
  for (int i = 0; i < kCH / 256; ++i) {
    int e = base + i * 256 + t;
    if (e < kE) {
      int d = dst[e];
      int b = d >> 8;
      bk[i] = b;
      unsigned lo = (unsigned)src[e] | ((unsigned)(d & 255) << 16);
      ent[i] = ((unsigned long long)(unsigned)__float_as_int(ts[e]) << 32) | lo;
      atomicAdd(&hist[b], 1);
    } else {
      bk[i] = -1;
    }
  }
  __syncthreads();
  for (int i = t; i < kNB; i += 256) {
    int c = hist[i];
    lbase[i] = c ? atomicAdd(gcursor + i, c) : 0;
  }
  __syncthreads();
  for (int i = t; i < kNB; i += 256) hist[i] = 0;
  __syncthreads();
#pragma unroll
  for (int i = 0; i < kCH / 256; ++i) {
    if (bk[i] >= 0) {
      int off = atomicAdd(&hist[bk[i]], 1);
      tmp[lbase[bk[i]] + off] = ent[i];
    }
  }
}

__global__ void __launch_bounds__(256) k_part2(
    const unsigned long long* __restrict__ tmp, const int* __restrict__ bucketbase,
    int* __restrict__ rowptr, int* __restrict__ csr_src,
    float* __restrict__ csr_ts) {
  __shared__ int cnt[256];
  __shared__ int sh[256];
  __shared__ int cur[256];
  int b = blockIdx.x;
  int t = threadIdx.x;
  int lo = bucketbase[b], hi = bucketbase[b + 1];
  int nnode = kN - b * 256;
  nnode = nnode < 256 ? nnode : 256;
  cnt[t] = 0;
  __syncthreads();
  for (int p = lo + t; p < hi; p += 256)
    atomicAdd(&cnt[((unsigned)tmp[p] >> 16) & 255], 1);
  __syncthreads();
  int v = cnt[t];
  sh[t] = v;
  __syncthreads();
  for (int off = 1; off < 256; off <<= 1) {
    int a = (t >= off) ? sh[t - off] : 0;
    __syncthreads();
    sh[t] += a;
    __syncthreads();
  }
  int nodebase = lo + sh[t] - v;
  if (t < nnode) rowptr[b * 256 + t] = nodebase;
  cur[t] = nodebase;
  __syncthreads();
  for (int p = lo + t; p < hi; p += 256) {
    unsigned long long e = tmp[p];
    unsigned elo = (unsigned)e;
    int pos = atomicAdd(&cur[(elo >> 16) & 255], 1);
    csr_src[pos] = (int)(elo & 0xffffu);
    csr_ts[pos] = __uint_as_float((unsigned)(e >> 32));
  }
}

// ---------- time encoding gather + zero pad: hb16[n,128..143]=t_enc, [144..159]=0 ----------
__global__ void __launch_bounds__(256) k_time_gather(
    const int* __restrict__ rowptr, const float* __restrict__ csr_ts,
    const float* __restrict__ tw, const float* __restrict__ tb,
    unsigned short* __restrict__ hb) {
  int n = blockIdx.x * 4 + (threadIdx.x >> 6);
  if (n >= kN) return;
  int lane = threadIdx.x & 63;
  int j = lane & 15, grp = lane >> 4;
  float w = tw[j], b = tb[j];
  int lo = rowptr[n], hi = rowptr[n + 1];
  float s = 0.f;
  for (int p = lo + grp; p < hi; p += 4) {
    s += cosf(csr_ts[p] * w + b);
  }
  s += __shfl_xor(s, 16);
  s += __shfl_xor(s, 32);
  if (grp == 0) hb[(size_t)n * 160 + 128 + j] = f2bf(s);
  if (grp == 1) hb[(size_t)n * 160 + 144 + j] = 0;
}

// ---------- MFMA projection: hb16[n,0..127] = bf16(x @ pw^T + bias), x read as f32 ----------
__global__ void __launch_bounds__(256) k_mfma_proj(
    const float* __restrict__ x, const unsigned short* __restrict__ wb,
    const float* __restrict__ bias, unsigned short* __restrict__ outb) {
  int n0 = blockIdx.x * 16;
  int wv = threadIdx.x >> 6, l = threadIdx.x & 63;
  int lr = l & 15, lk = l >> 4;
  const int K = 128;
  int jt0 = 2 * wv, jt1 = 2 * wv + 1;
  const float* arow = x + (size_t)(n0 + lr) * K + lk * 8;
  const unsigned short* brow0 = wb + (size_t)(jt0 * 16 + lr) * K + lk * 8;
  const unsigned short* brow1 = wb + (size_t)(jt1 * 16 + lr) * K + lk * 8;
  f32x4 acc0 = {0.f, 0.f, 0.f, 0.f}, acc1 = {0.f, 0.f, 0.f, 0.f};
#pragma unroll
  for (int c = 0; c < 4; ++c) {
    float4 alo = *(const float4*)(arow + c * 32);
    float4 ahi = *(const float4*)(arow + c * 32 + 4);
    bf16x8 a;
    a[0] = (short)f2bf(alo.x); a[1] = (short)f2bf(alo.y);
    a[2] = (short)f2bf(alo.z); a[3] = (short)f2bf(alo.w);
    a[4] = (short)f2bf(ahi.x); a[5] = (short)f2bf(ahi.y);
    a[6] = (short)f2bf(ahi.z); a[7] = (short)f2bf(ahi.w);
    acc0 = __builtin_amdgcn_mfma_f32_16x16x32_bf16(a, *(const bf16x8*)(brow0 + c * 32), acc0, 0, 0, 0);
    acc1 = __builtin_amdgcn_mfma_f32_16x16x32_bf16(a, *(const bf16x8*)(brow1 + c * 32), acc1, 0, 0, 0);
  }
  int j0 = jt0 * 16 + lr, j1 = jt1 * 16 + lr;
  float bb0 = bias[j0], bb1 = bias[j1];
#pragma unroll
  for (int r = 0; r < 4; ++r) {
    int node = n0 + lk * 4 + r;
    outb[(size_t)node * 160 + j0] = f2bf(acc0[r] + bb0);
    outb[(size_t)node * 160 + j1] = f2bf(acc1[r] + bb1);
  }
}

// ---------- MFMA xh = h @ W^T (bf16 in/out) fused with att dots ----------
__global__ void __launch_bounds__(256) k_mfma_xh_att(
    const unsigned short* __restrict__ hb, int K,
    const unsigned short* __restrict__ wb,
    const float* __restrict__ att_s, const float* __restrict__ att_d,
    unsigned short* __restrict__ xh, float* __restrict__ a_src,
    float* __restrict__ a_dst) {
  int n0 = blockIdx.x * 16;
  int wv = threadIdx.x >> 6, l = threadIdx.x & 63;
  int lr = l & 15, lk = l >> 4;
  int jt0 = 2 * wv, jt1 = 2 * wv + 1;
  const unsigned short* arow = hb + (size_t)(n0 + lr) * K + lk * 8;
  const unsigned short* brow0 = wb + (size_t)(jt0 * 16 + lr) * K + lk * 8;
  const unsigned short* brow1 = wb + (size_t)(jt1 * 16 + lr) * K + lk * 8;
  f32x4 acc0 = {0.f, 0.f, 0.f, 0.f}, acc1 = {0.f, 0.f, 0.f, 0.f};
  int nch = K >> 5;
  for (int c = 0; c < nch; ++c) {
    bf16x8 a = *(const bf16x8*)(arow + c * 32);
    acc0 = __builtin_amdgcn_mfma_f32_16x16x32_bf16(a, *(const bf16x8*)(brow0 + c * 32), acc0, 0, 0, 0);
    acc1 = __builtin_amdgcn_mfma_f32_16x16x32_bf16(a, *(const bf16x8*)(brow1 + c * 32), acc1, 0, 0, 0);
  }
  int j0 = jt0 * 16 + lr, j1 = jt1 * 16 + lr;
  float as0 = att_s[j0], as1 = att_s[j1];
  float ad0 = att_d[j0], ad1 = att_d[j1];
#pragma unroll
  for (int r = 0; r < 4; ++r) {
    int node = n0 + lk * 4 + r;
    float d0 = acc0[r], d1 = acc1[r];
    xh[(size_t)node * 128 + j0] = f2bf(d0);
    xh[(size_t)node * 128 + j1] = f2bf(d1);
    float vs = d0 * as0 + d1 * as1;
    float vd = d0 * ad0 + d1 * ad1;
    vs += __shfl_xor(vs, 1); vs += __shfl_xor(vs, 2);
    vs += __shfl_xor(vs, 4); vs += __shfl_xor(vs, 8);
    vd += __shfl_xor(vd, 1); vd += __shfl_xor(vd, 2);
    vd += __shfl_xor(vd, 4); vd += __shfl_xor(vd, 8);
    if (lr == 0) {
      a_src[node * 4 + wv] = vs;
      a_dst[node * 4 + wv] = vd;
    }
  }
}

// ---------- GAT: exact softmax (no max shift) + bias + LN + ReLU, bf16 out ----------
// one wave per node; 16 lanes per edge (8 channels each), 4 edges per batch,
// 2-deep software pipeline.
__global__ void __launch_bounds__(256) k_gat_agg(
    const unsigned short* __restrict__ xh, const float* __restrict__ a_src,
    const float* __restrict__ a_dst,
    const int* __restrict__ rowptr, const int* __restrict__ csr_src,
    const float* __restrict__ gb, const float* __restrict__ lw,
    const float* __restrict__ lb, unsigned short* __restrict__ outb) {
  int n = blockIdx.x * 4 + (threadIdx.x >> 6);
  if (n >= kN) return;
  int lane = threadIdx.x & 63;
  int eg = lane >> 4;         // edge group (0..3)
  int li = lane & 15;         // lane-in-group; channels li*8..+7
  int hd = li >> 2;           // head of this lane's channels
  float ad = a_dst[n * 4 + hd];

  float den = 0.f;
  float a0 = 0.f, a1 = 0.f, a2 = 0.f, a3 = 0.f, a4 = 0.f, a5 = 0.f, a6 = 0.f, a7 = 0.f;

  // self-loop (group 0 only)
  if (eg == 0) {
    float w_self = __expf(leaky(a_src[n * 4 + hd] + ad));
    den = w_self;
    uint4 u = ((const uint4*)(xh + (size_t)n * 128))[li];
    a0 = w_self * bflo(u.x); a1 = w_self * bfhi(u.x);
    a2 = w_self * bflo(u.y); a3 = w_self * bfhi(u.y);
    a4 = w_self * bflo(u.z); a5 = w_self * bfhi(u.z);
    a6 = w_self * bflo(u.w); a7 = w_self * bfhi(u.w);
  }

  int lo = rowptr[n], hi = rowptr[n + 1];
  int s_cur = -1;
  uint4 u_cur = {0, 0, 0, 0};
  float asrc_cur = 0.f;
  {
    int e = lo + eg;
    if (e < hi) {
      s_cur = csr_src[e];
      u_cur = ((const uint4*)(xh + (size_t)s_cur * 128))[li];
      asrc_cur = a_src[s_cur * 4 + hd];
    }
  }
  for (int p = lo; p < hi; p += 4) {
    int s_next = -1;
    uint4 u_next = {0, 0, 0, 0};
    float asrc_next = 0.f;
    int en = p + 4 + eg;
    if (en < hi) {
      s_next = csr_src[en];
      u_next = ((const uint4*)(xh + (size_t)s_next * 128))[li];
      asrc_next = a_src[s_next * 4 + hd];
    }
    if (s_cur >= 0) {
      float wv = __expf(leaky(asrc_cur + ad));
      den += wv;
      a0 += wv * bflo(u_cur.x); a1 += wv * bfhi(u_cur.x);
      a2 += wv * bflo(u_cur.y); a3 += wv * bfhi(u_cur.y);
      a4 += wv * bflo(u_cur.z); a5 += wv * bfhi(u_cur.z);
      a6 += wv * bflo(u_cur.w); a7 += wv * bfhi(u_cur.w);
    }
    s_cur = s_next;
    u_cur = u_next;
    asrc_cur = asrc_next;
  }

  // cross-group combine (lanes with same li across eg): xor 16, 32
#pragma unroll
  for (int off = 16; off <= 32; off <<= 1) {
    den += __shfl_xor(den, off);
    a0 += __shfl_xor(a0, off); a1 += __shfl_xor(a1, off);
    a2 += __shfl_xor(a2, off); a3 += __shfl_xor(a3, off);
    a4 += __shfl_xor(a4, off); a5 += __shfl_xor(a5, off);
    a6 += __shfl_xor(a6, off); a7 += __shfl_xor(a7, off);
  }

  float inv = 1.f / den;
  int c0 = li * 8;
  float4 gbl = *(const float4*)(gb + c0);
  float4 gbh = *(const float4*)(gb + c0 + 4);
  float v0 = a0 * inv + gbl.x, v1 = a1 * inv + gbl.y;
  float v2 = a2 * inv + gbl.z, v3 = a3 * inv + gbl.w;
  float v4 = a4 * inv + gbh.x, v5 = a5 * inv + gbh.y;
  float v6 = a6 * inv + gbh.z, v7 = a7 * inv + gbh.w;
  float s = v0 + v1 + v2 + v3 + v4 + v5 + v6 + v7;
  float sq = v0*v0 + v1*v1 + v2*v2 + v3*v3 + v4*v4 + v5*v5 + v6*v6 + v7*v7;
#pragma unroll
  for (int off = 1; off <= 8; off <<= 1) {
    s += __shfl_xor(s, off);
    sq += __shfl_xor(sq, off);
  }
  float mean = s * (1.f / 128.f);
  float var = sq * (1.f / 128.f) - mean * mean;
  float rs = rsqrtf(var + LN_EPS);
  if (eg == 0) {
    float4 lwl = *(const float4*)(lw + c0), lwh = *(const float4*)(lw + c0 + 4);
    float4 lbl = *(const float4*)(lb + c0), lbh = *(const float4*)(lb + c0 + 4);
    float y0 = fmaxf((v0 - mean) * rs * lwl.x + lbl.x, 0.f);
    float y1 = fmaxf((v1 - mean) * rs * lwl.y + lbl.y, 0.f);
    float y2 = fmaxf((v2 - mean) * rs * lwl.z + lbl.z, 0.f);
    float y3 = fmaxf((v3 - mean) * rs * lwl.w + lbl.w, 0.f);
    float y4 = fmaxf((v4 - mean) * rs * lwh.x + lbh.x, 0.f);
    float y5 = fmaxf((v5 - mean) * rs * lwh.y + lbh.y, 0.f);
    float y6 = fmaxf((v6 - mean) * rs * lwh.z + lbh.z, 0.f);
    float y7 = fmaxf((v7 - mean) * rs * lwh.w + lbh.w, 0.f);
    uint4 o;
    o.x = (unsigned)f2bf(y0) | ((unsigned)f2bf(y1) << 16);
    o.y = (unsigned)f2bf(y2) | ((unsigned)f2bf(y3) << 16);
    o.z = (unsigned)f2bf(y4) | ((unsigned)f2bf(y5) << 16);
    o.w = (unsigned)f2bf(y6) | ((unsigned)f2bf(y7) << 16);
    *(uint4*)(outb + (size_t)n * 128 + c0) = o;
  }
}

// ---------- pooling stage 1 (bf16 input): 64 groups x 16 chunks ----------
__global__ void __launch_bounds__(128) k_pool1(
    const unsigned short* __restrict__ h, const int* __restrict__ batch,
    float* __restrict__ psum, float* __restrict__ pmax) {
  int g = blockIdx.x >> 4, chunk = blockIdx.x & (kPOOLC - 1);
  int c = threadIdx.x;  // 128 channels
  int lo, hi;
  { int a = 0, b = kN; while (a < b) { int m = (a + b) >> 1; if (batch[m] < g) a = m + 1; else b = m; } lo = a; }
  { int a = 0, b = kN; while (a < b) { int m = (a + b) >> 1; if (batch[m] < g + 1) a = m + 1; else b = m; } hi = a; }
  int len = hi - lo;
  int c0 = lo + (int)(((long long)len * chunk) / kPOOLC);
  int c1 = lo + (int)(((long long)len * (chunk + 1)) / kPOOLC);
  float s = 0.f, mx = -INFINITY;
  for (int n = c0; n < c1; ++n) {
    float v = __uint_as_float(((unsigned)h[(size_t)n * 128 + c]) << 16);
    s += v;
    mx = fmaxf(mx, v);
  }
  psum[(size_t)blockIdx.x * 128 + c] = s;
  pmax[(size_t)blockIdx.x * 128 + c] = mx;
}

// ---------- pooling stage 2 + classifier (fused; one block per group) ----------
__global__ void __launch_bounds__(128) k_pool2_cls(
    const float* __restrict__ psum, const float* __restrict__ pmax,
    const int* __restrict__ batch,
    const float* __restrict__ w1t, const float* __restrict__ b1,
    const float* __restrict__ w2, const float* __restrict__ b2,
    float* __restrict__ out) {
  __shared__ float row[256];
  __shared__ float o1[128];
  int g = blockIdx.x;
  int c = threadIdx.x;
  int lo, hi;
  { int a = 0, b = kN; while (a < b) { int m = (a + b) >> 1; if (batch[m] < g) a = m + 1; else b = m; } lo = a; }
  { int a = 0, b = kN; while (a < b) { int m = (a + b) >> 1; if (batch[m] < g + 1) a = m + 1; else b = m; } hi = a; }
  float s = 0.f, mx = -INFINITY;
#pragma unroll
  for (int k = 0; k < kPOOLC; ++k) {
    s += psum[(size_t)(g * kPOOLC + k) * 128 + c];
    mx = fmaxf(mx, pmax[(size_t)(g * kPOOLC + k) * 128 + c]);
  }
  int cnt = hi - lo;
  row[c] = (cnt > 0) ? s / (float)cnt : 0.f;
  row[c + 128] = mx;
  __syncthreads();
  float t = b1[c];
  for (int k = 0; k < 256; ++k) t += row[k] * w1t[k * 128 + c];
  o1[c] = fmaxf(t, 0.f);
  __syncthreads();
  if (c < 2) {
    float r = b2[c];
    for (int j = 0; j < 128; ++j) r += o1[j] * w2[c * 128 + j];
    out[g * 2 + c] = r;
  }
}

extern "C" void kernel_launch(void* const* d_in, const int* in_sizes, int n_in,
                              void* d_out, int out_size, void* d_ws, size_t ws_size,
                              hipStream_t stream) {
  const float* x      = (const float*)d_in[0];
  const int*   ei     = (const int*)d_in[1];
  const float* ts     = (const float*)d_in[2];
  const int*   batch  = (const int*)d_in[3];
  const float* time_w = (const float*)d_in[4];
  const float* time_b = (const float*)d_in[5];
  const float* proj_w = (const float*)d_in[6];
  const float* proj_b = (const float*)d_in[7];
  const float* g0w    = (const float*)d_in[8];
  const float* as0    = (const float*)d_in[9];
  const float* ad0    = (const float*)d_in[10];
  const float* g0b    = (const float*)d_in[11];
  const float* ln0w   = (const float*)d_in[12];
  const float* ln0b   = (const float*)d_in[13];
  const float* g1w    = (const float*)d_in[14];
  const float* as1    = (const float*)d_in[15];
  const float* ad1    = (const float*)d_in[16];
  const float* g1b    = (const float*)d_in[17];
  const float* ln1w   = (const float*)d_in[18];
  const float* ln1b   = (const float*)d_in[19];
  const float* c1w    = (const float*)d_in[20];
  const float* c1b    = (const float*)d_in[21];
  const float* c2w    = (const float*)d_in[22];
  const float* c2b    = (const float*)d_in[23];
  float* out = (float*)d_out;

  const int* src = ei;
  const int* dst = ei + kE;

  // ---- workspace layout (bytes; all large regions 16B-aligned) ----
  char* p = (char*)d_ws;
  unsigned short* xh   = (unsigned short*)p; p += (size_t)kN * 128 * 2;
  unsigned short* hb16 = (unsigned short*)p; p += (size_t)kN * 160 * 2;  // layer-0 input (padded K=160)
  unsigned short* h1b16= (unsigned short*)p; p += (size_t)kN * 128 * 2;  // gat outputs (bf16)
  float* a_src = (float*)p; p += (size_t)kN * 4 * 4;
  float* a_dst = (float*)p; p += (size_t)kN * 4 * 4;
  unsigned short* pwb = (unsigned short*)p; p += 128 * 128 * 2;
  unsigned short* w0b = (unsigned short*)p; p += 128 * 160 * 2;
  unsigned short* w1b = (unsigned short*)p; p += 128 * 128 * 2;
  float* c1T = (float*)p; p += 256 * 128 * 4;
  int* csr_src = (int*)p; p += (size_t)kE * 4;
  float* csr_ts = (float*)p; p += (size_t)kE * 4;
  unsigned long long* tmp = (unsigned long long*)p; p += (size_t)kE * 8;
  float* psum = (float*)p; p += (size_t)kG * kPOOLC * 128 * 4;
  float* pmax = (float*)p; p += (size_t)kG * kPOOLC * 128 * 4;
  int* rowptr = (int*)p; p += (kN + 1) * 4;
  int* gbhist = (int*)p; p += kNB * 4;
  int* bucketbase = (int*)p; p += (kNB + 1) * 4;
  int* gcursor = (int*)p; p += kNB * 4;

  // ---- prep (hist + weights; gbhist zeroed first) ----
  hipMemsetAsync(gbhist, 0, kNB * sizeof(int), stream);
  k_prep<<<kPB + kPREPB, 256, 0, stream>>>(dst, gbhist, c1w, c1T, proj_w, pwb,
                                           g0w, w0b, g1w, w1b);

  // ---- CSR build ----
  k_bprefix<<<1, 256, 0, stream>>>(gbhist, bucketbase, gcursor, rowptr);
  k_part1<<<kPB, 256, 0, stream>>>(src, dst, ts, gcursor, tmp);
  k_part2<<<kNB, 256, 0, stream>>>(tmp, bucketbase, rowptr, csr_src, csr_ts);

  // ---- projection (MFMA, reads f32 x) + time encoding (incl. zero pad) ----
  k_mfma_proj<<<kN / 16, 256, 0, stream>>>(x, pwb, proj_b, hb16);
  k_time_gather<<<kN / 4, 256, 0, stream>>>(rowptr, csr_ts, time_w, time_b, hb16);

  // ---- GAT layer 0 ----
  k_mfma_xh_att<<<kN / 16, 256, 0, stream>>>(hb16, 160, w0b, as0, ad0, xh, a_src, a_dst);
  k_gat_agg<<<kN / 4, 256, 0, stream>>>(xh, a_src, a_dst, rowptr, csr_src,
                                        g0b, ln0w, ln0b, h1b16);

  // ---- GAT layer 1 ----
  k_mfma_xh_att<<<kN / 16, 256, 0, stream>>>(h1b16, 128, w1b, as1, ad1, xh, a_src, a_dst);
  k_gat_agg<<<kN / 4, 256, 0, stream>>>(xh, a_src, a_dst, rowptr, csr_src,
                                        g1b, ln1w, ln1b, h1b16);

  // ---- pooling + classifier ----
  k_pool1<<<kG * kPOOLC, 128, 0, stream>>>(h1b16, batch, psum, pmax);
  k_pool2_cls<<<kG, 128, 0, stream>>>(psum, pmax, batch, c1T, c1b, c2w, c2b, out);
}